// Round 19
// baseline (103.973 us; speedup 1.0000x reference)
//
#include <hip/hip_runtime.h>
#include <hip/hip_bf16.h>

typedef __attribute__((ext_vector_type(8))) short bf16x8;
typedef __attribute__((ext_vector_type(4))) float f32x4;
typedef __attribute__((ext_vector_type(4))) unsigned int u32x4;

static constexpr int BB = 2, T = 2048, C = 1024, NH = 16, DH = 64;

__device__ __forceinline__ void gload16(const void* g, void* l) {
  __builtin_amdgcn_global_load_lds(
      (const __attribute__((address_space(1))) unsigned int*)g,
      (__attribute__((address_space(3))) unsigned int*)l, 16, 0, 0);
}

__device__ __forceinline__ unsigned pack_bf16(float lo, float hi) {
  unsigned a = (unsigned)__bfloat16_as_ushort(__float2bfloat16(lo));
  unsigned b = (unsigned)__bfloat16_as_ushort(__float2bfloat16(hi));
  return a | (b << 16);
}

__device__ __forceinline__ float fast_exp2(float x) {
#if __has_builtin(__builtin_amdgcn_exp2f)
  return __builtin_amdgcn_exp2f(x);
#else
  return exp2f(x);
#endif
}

// ---------------- fused prep: x cvt + both weight transposes ----------------
__global__ __launch_bounds__(256) void k_prep(const float* __restrict__ x,
                                              __hip_bfloat16* __restrict__ xb,
                                              const float* __restrict__ wq,
                                              __hip_bfloat16* __restrict__ wqt,
                                              const float* __restrict__ wp,
                                              __hip_bfloat16* __restrict__ wpt) {
  __shared__ float tile[32][33];
  const int bid = blockIdx.x, tid = threadIdx.x;
  if (bid < 4096) {
    const int i = bid * 256 + tid;
    float4 v = reinterpret_cast<const float4*>(x)[i];
    __hip_bfloat16 h[4];
    h[0] = __float2bfloat16(v.x); h[1] = __float2bfloat16(v.y);
    h[2] = __float2bfloat16(v.z); h[3] = __float2bfloat16(v.w);
    reinterpret_cast<uint2*>(xb)[i] = *reinterpret_cast<uint2*>(h);
    return;
  }
  const float* in;
  __hip_bfloat16* out;
  int K, N, bx, by;
  if (bid < 7168) {
    const int b2 = bid - 4096;
    in = wq; out = wqt; K = 1024; N = 3072; bx = b2 % 96; by = b2 / 96;
  } else {
    const int b2 = bid - 7168;
    in = wp; out = wpt; K = 1024; N = 1024; bx = b2 % 32; by = b2 / 32;
  }
  const int n0 = bx * 32, k0 = by * 32;
  const int tx = tid & 31, ty = tid >> 5;  // 32 x 8
#pragma unroll
  for (int i = 0; i < 32; i += 8)
    tile[ty + i][tx] = in[(size_t)(k0 + ty + i) * N + n0 + tx];
  __syncthreads();
#pragma unroll
  for (int i = 0; i < 32; i += 8)
    out[(size_t)(n0 + ty + i) * K + k0 + tx] = __float2bfloat16(tile[tx][ty + i]);
}

// ---------------- QKV GEMM: 128x128 tile, BK=64, 4 waves, 2 blocks/CU -------------
// r13-proven K-loop. Epilogue: Q/K direct scatter; V via per-wave LDS transpose.
__global__ __launch_bounds__(256, 2) void k_gemmqkv(
    const __hip_bfloat16* __restrict__ A, const __hip_bfloat16* __restrict__ Bt,
    const float* __restrict__ bias,
    __hip_bfloat16* __restrict__ oq, __hip_bfloat16* __restrict__ okk,
    __hip_bfloat16* __restrict__ ovt) {
  __shared__ __align__(16) char smem[65536];  // [buf][A 16K | B 16K]
  const int tid = threadIdx.x;
  const int w = tid >> 6, lane = tid & 63;
  const int lr = lane & 15, lg = lane >> 4;
  const int wm = (w >> 1) * 64, wn = (w & 1) * 64;
  const int m0 = blockIdx.x * 128, n0 = blockIdx.y * 128;

  const int scol = (((tid & 7) ^ ((tid >> 3) & 7)) << 4);
  const char* Ag = (const char*)A + (size_t)(m0 + (tid >> 3)) * 2048 + scol;
  const char* Bg = (const char*)Bt + (size_t)(n0 + (tid >> 3)) * 2048 + scol;
  const size_t ldst = (size_t)(tid & ~63) * 16;  // wave-uniform LDS base

  auto stage = [&](int ks, char* lA) {  // A at +0, B at +16384
    const char* ag = Ag + (size_t)ks * 128;
    const char* bg = Bg + (size_t)ks * 128;
    char* lB = lA + 16384;
#pragma unroll
    for (int j = 0; j < 4; ++j) {
      gload16(ag + (size_t)j * 65536, lA + j * 4096 + ldst);
      gload16(bg + (size_t)j * 65536, lB + j * 4096 + ldst);
    }
  };

  const int swz = (lr & 7) << 4;
  const int aofs = (wm + lr) * 128;
  const int bofs = 16384 + (wn + lr) * 128;
  const int x0 = (lg * 16) ^ swz;
  const int x1 = (64 + lg * 16) ^ swz;
  const char* A00 = smem + aofs + x0;
  const char* A01 = smem + aofs + x1;
  const char* B00 = smem + bofs + x0;
  const char* B01 = smem + bofs + x1;
  const char* A10 = A00 + 32768;
  const char* A11 = A01 + 32768;
  const char* B10 = B00 + 32768;
  const char* B11 = B01 + 32768;

  f32x4 acc[4][4] = {};

  auto compute = [&](const char* pA0, const char* pA1, const char* pB0,
                     const char* pB1) {
#pragma unroll
    for (int kk = 0; kk < 2; ++kk) {
      const char* pA = kk ? pA1 : pA0;
      const char* pB = kk ? pB1 : pB0;
      bf16x8 a[4], b[4];
#pragma unroll
      for (int mi = 0; mi < 4; ++mi)
        a[mi] = *reinterpret_cast<const bf16x8*>(pA + mi * 2048);
#pragma unroll
      for (int ni = 0; ni < 4; ++ni)
        b[ni] = *reinterpret_cast<const bf16x8*>(pB + ni * 2048);
      __builtin_amdgcn_s_setprio(1);
#pragma unroll
      for (int mi = 0; mi < 4; ++mi)
#pragma unroll
        for (int ni = 0; ni < 4; ++ni)
          acc[mi][ni] =
              __builtin_amdgcn_mfma_f32_16x16x32_bf16(a[mi], b[ni], acc[mi][ni], 0, 0, 0);
      __builtin_amdgcn_s_setprio(0);
    }
  };

  stage(0, smem);
  __syncthreads();
  for (int it = 0; it < 8; ++it) {
    stage(2 * it + 1, smem + 32768);
    compute(A00, A01, B00, B01);
    __syncthreads();
    if (it < 7) stage(2 * it + 2, smem);
    compute(A10, A11, B10, B11);
    __syncthreads();
  }

  const int region = n0 >> 10;  // 0=Q 1=K 2=V
  float bias_r[4];
#pragma unroll
  for (int ni = 0; ni < 4; ++ni) bias_r[ni] = bias[n0 + wn + ni * 16 + lr];

  if (region < 2) {
    __hip_bfloat16* dst = (region == 0) ? oq : okk;
    const float sc = (region == 0) ? 0.1803368801111244f : 1.0f;
#pragma unroll
    for (int mi = 0; mi < 4; ++mi) {
#pragma unroll
      for (int ni = 0; ni < 4; ++ni) {
        const int nn = n0 + wn + ni * 16 + lr;
        const int cc = nn & 1023, h = cc >> 6, d = cc & 63;
#pragma unroll
        for (int r = 0; r < 4; ++r) {
          const int m = m0 + wm + mi * 16 + lg * 4 + r;
          const int bb = m >> 11, t = m & 2047;
          dst[((size_t)(bb * NH + h) * T + t) * DH + d] =
              __float2bfloat16((acc[mi][ni][r] + bias_r[ni]) * sc);
        }
      }
    }
  } else {
    char* E = smem + w * 8192;
#pragma unroll
    for (int mi = 0; mi < 4; ++mi) {
      const int mlb = mi * 16 + lg * 4;
      const int mp = (mlb & 35) | ((mlb & 12) << 1) | ((mlb & 16) >> 2);
#pragma unroll
      for (int ni = 0; ni < 4; ++ni) {
        const int dl = ni * 16 + lr;
        const int rs = (dl & 7) << 4;
        const unsigned v01 = pack_bf16(acc[mi][ni][0] + bias_r[ni],
                                       acc[mi][ni][1] + bias_r[ni]);
        const unsigned v23 = pack_bf16(acc[mi][ni][2] + bias_r[ni],
                                       acc[mi][ni][3] + bias_r[ni]);
        *reinterpret_cast<unsigned*>(&E[dl * 128 + ((mp * 2) ^ rs)]) = v01;
        *reinterpret_cast<unsigned*>(&E[dl * 128 + (((mp + 2) * 2) ^ rs)]) = v23;
      }
    }
    const int hh = ((n0 + wn) & 1023) >> 6;
    const int bb = m0 >> 11, tb = (m0 & 2047) + wm;
    __hip_bfloat16* dst = ovt + ((size_t)(bb * NH + hh) * DH) * T + tb;
    const int lrs = (lane & 7) << 4;
#pragma unroll
    for (int j = 0; j < 8; ++j) {
      u32x4 v = *reinterpret_cast<const u32x4*>(&E[lane * 128 + ((j * 16) ^ lrs)]);
      *reinterpret_cast<u32x4*>(&dst[(size_t)lane * T + j * 8]) = v;
    }
  }
}

// ---------------- proj GEMM: r13 BK=64 skeleton, fp32 out + bias ------------------
__global__ __launch_bounds__(256, 2) void k_gemmproj(
    const __hip_bfloat16* __restrict__ A, const __hip_bfloat16* __restrict__ Bt,
    const float* __restrict__ bias, float* __restrict__ of) {
  constexpr int N = 1024;
  __shared__ __align__(16) char smem[65536];
  const int tid = threadIdx.x;
  const int w = tid >> 6, lane = tid & 63;
  const int lr = lane & 15, lg = lane >> 4;
  const int wm = (w >> 1) * 64, wn = (w & 1) * 64;
  const int m0 = blockIdx.x * 128, n0 = blockIdx.y * 128;

  const int scol = (((tid & 7) ^ ((tid >> 3) & 7)) << 4);
  const char* Ag = (const char*)A + (size_t)(m0 + (tid >> 3)) * 2048 + scol;
  const char* Bg = (const char*)Bt + (size_t)(n0 + (tid >> 3)) * 2048 + scol;
  const size_t ldst = (size_t)(tid & ~63) * 16;

  auto stage = [&](int ks, char* lA) {
    const char* ag = Ag + (size_t)ks * 128;
    const char* bg = Bg + (size_t)ks * 128;
    char* lB = lA + 16384;
#pragma unroll
    for (int j = 0; j < 4; ++j) {
      gload16(ag + (size_t)j * 65536, lA + j * 4096 + ldst);
      gload16(bg + (size_t)j * 65536, lB + j * 4096 + ldst);
    }
  };

  const int swz = (lr & 7) << 4;
  const int aofs = (wm + lr) * 128;
  const int bofs = 16384 + (wn + lr) * 128;
  const int x0 = (lg * 16) ^ swz;
  const int x1 = (64 + lg * 16) ^ swz;
  const char* A00 = smem + aofs + x0;
  const char* A01 = smem + aofs + x1;
  const char* B00 = smem + bofs + x0;
  const char* B01 = smem + bofs + x1;
  const char* A10 = A00 + 32768;
  const char* A11 = A01 + 32768;
  const char* B10 = B00 + 32768;
  const char* B11 = B01 + 32768;

  f32x4 acc[4][4] = {};

  auto compute = [&](const char* pA0, const char* pA1, const char* pB0,
                     const char* pB1) {
#pragma unroll
    for (int kk = 0; kk < 2; ++kk) {
      const char* pA = kk ? pA1 : pA0;
      const char* pB = kk ? pB1 : pB0;
      bf16x8 a[4], b[4];
#pragma unroll
      for (int mi = 0; mi < 4; ++mi)
        a[mi] = *reinterpret_cast<const bf16x8*>(pA + mi * 2048);
#pragma unroll
      for (int ni = 0; ni < 4; ++ni)
        b[ni] = *reinterpret_cast<const bf16x8*>(pB + ni * 2048);
      __builtin_amdgcn_s_setprio(1);
#pragma unroll
      for (int mi = 0; mi < 4; ++mi)
#pragma unroll
        for (int ni = 0; ni < 4; ++ni)
          acc[mi][ni] =
              __builtin_amdgcn_mfma_f32_16x16x32_bf16(a[mi], b[ni], acc[mi][ni], 0, 0, 0);
      __builtin_amdgcn_s_setprio(0);
    }
  };

  stage(0, smem);
  __syncthreads();
  for (int it = 0; it < 8; ++it) {
    stage(2 * it + 1, smem + 32768);
    compute(A00, A01, B00, B01);
    __syncthreads();
    if (it < 7) stage(2 * it + 2, smem);
    compute(A10, A11, B10, B11);
    __syncthreads();
  }

  float bias_r[4];
#pragma unroll
  for (int ni = 0; ni < 4; ++ni) bias_r[ni] = bias[n0 + wn + ni * 16 + lr];

#pragma unroll
  for (int mi = 0; mi < 4; ++mi)
#pragma unroll
    for (int ni = 0; ni < 4; ++ni) {
      const int n = n0 + wn + ni * 16 + lr;
#pragma unroll
      for (int r = 0; r < 4; ++r) {
        const int m = m0 + wm + mi * 16 + lg * 4 + r;
        of[(size_t)m * N + n] = acc[mi][ni][r] + bias_r[ni];
      }
    }
}

// ---------------- flash attention v10: 32q/wave + KV-tile 128 (half the barriers) --
// r18 body; one 32KB stage + one sync pair now covers 128 kv (two compute-64
// calls). LDS 2 bufs x [K0 8K | V0 8K | K1 8K | V1 8K] = 64KB, 2 blocks/CU.
__global__ __launch_bounds__(256, 2) void k_attn(const __hip_bfloat16* __restrict__ Q,
                                                 const __hip_bfloat16* __restrict__ Kc,
                                                 const __hip_bfloat16* __restrict__ Vt,
                                                 __hip_bfloat16* __restrict__ O) {
  __shared__ __align__(16) char smem[2][32768];
  const int tid = threadIdx.x;
  const int w = tid >> 6, lane = tid & 63;
  const int lr = lane & 15, lg = lane >> 4;
  const int n = blockIdx.x;                       // 512 blocks, 1-D
  const int xtile = (n >> 3) & 15;
  const int bh = ((n >> 7) << 3) | (n & 7);
  const int b = bh >> 4, h = bh & 15;
  const int t0 = xtile * 128 + w * 32;
  const __hip_bfloat16* Qh = Q + (size_t)bh * T * DH;
  const char* Kbase = (const char*)(Kc + (size_t)bh * T * DH);   // rows of 128B
  const char* Vbase = (const char*)(Vt + (size_t)bh * DH * T);   // rows of 4096B

  const int srow = tid >> 3;
  const int scol = (((tid & 7) ^ (srow & 7)) << 4);
  const size_t ldst = (size_t)(tid & ~63) * 16;
  const char* Kg = Kbase + (size_t)srow * 128 + scol;
  const char* Vg = Vbase + (size_t)srow * 4096 + scol;

  const int swz = (lr & 7) << 4;
  const int lbA = lr * 128 + ((lg * 16) ^ swz);
  const int lbB = lr * 128 + ((64 + lg * 16) ^ swz);
  const char* kA0 = smem[0] + lbA;   // buf0 half0; half1 at +16384
  const char* kB0 = smem[0] + lbB;
  const char* kA1 = smem[1] + lbA;   // buf1
  const char* kB1 = smem[1] + lbB;

  // stage 128 kv: [K kv..+63 | V cols kv..+63 | K kv+64..+127 | V cols kv+64..]
  auto stage = [&](int kv, char* buf) {
    const char* kg = Kg + (size_t)kv * 128;
    const char* vg = Vg + (size_t)kv * 2;
    gload16(kg, buf + ldst);
    gload16(kg + 4096, buf + 4096 + ldst);
    gload16(vg, buf + 8192 + ldst);
    gload16(vg + 131072, buf + 12288 + ldst);
    gload16(kg + 8192, buf + 16384 + ldst);
    gload16(kg + 12288, buf + 20480 + ldst);
    gload16(vg + 128, buf + 24576 + ldst);
    gload16(vg + 131072 + 128, buf + 28672 + ldst);
  };

  bf16x8 q0[2], q1[2];
#pragma unroll
  for (int kf = 0; kf < 2; ++kf) {
    q0[kf] = *reinterpret_cast<const bf16x8*>(&Qh[(size_t)(t0 + lr) * DH + kf * 32 + lg * 8]);
    q1[kf] = *reinterpret_cast<const bf16x8*>(&Qh[(size_t)(t0 + 16 + lr) * DH + kf * 32 + lg * 8]);
  }

  f32x4 o0[4] = {}, o1[4] = {};
  float l0 = 0.f, l1 = 0.f;

  auto compute = [&](const char* kA, const char* kB) {
    bf16x8 bk[4][2];
#pragma unroll
    for (int nj = 0; nj < 4; ++nj) {
      bk[nj][0] = *reinterpret_cast<const bf16x8*>(kA + nj * 2048);
      bk[nj][1] = *reinterpret_cast<const bf16x8*>(kB + nj * 2048);
    }

    f32x4 s0[4] = {}, s1[4] = {};
    __builtin_amdgcn_s_setprio(1);
#pragma unroll
    for (int nj = 0; nj < 4; ++nj) {
      s0[nj] = __builtin_amdgcn_mfma_f32_16x16x32_bf16(bk[nj][0], q0[0], s0[nj], 0, 0, 0);
      s0[nj] = __builtin_amdgcn_mfma_f32_16x16x32_bf16(bk[nj][1], q0[1], s0[nj], 0, 0, 0);
      s1[nj] = __builtin_amdgcn_mfma_f32_16x16x32_bf16(bk[nj][0], q1[0], s1[nj], 0, 0, 0);
      s1[nj] = __builtin_amdgcn_mfma_f32_16x16x32_bf16(bk[nj][1], q1[1], s1[nj], 0, 0, 0);
    }
    __builtin_amdgcn_s_setprio(0);

    bf16x8 av[4][2];
#pragma unroll
    for (int nd = 0; nd < 4; ++nd) {
      av[nd][0] = *reinterpret_cast<const bf16x8*>(kA + 8192 + nd * 2048);
      av[nd][1] = *reinterpret_cast<const bf16x8*>(kB + 8192 + nd * 2048);
    }

#pragma unroll
    for (int nj = 0; nj < 4; ++nj)
#pragma unroll
      for (int r = 0; r < 4; ++r) {
        s0[nj][r] = fast_exp2(s0[nj][r]);
        s1[nj][r] = fast_exp2(s1[nj][r]);
      }
    {
      float a0 = (s0[0][0] + s0[0][1]) + (s0[0][2] + s0[0][3]);
      float a1 = (s0[1][0] + s0[1][1]) + (s0[1][2] + s0[1][3]);
      float a2 = (s0[2][0] + s0[2][1]) + (s0[2][2] + s0[2][3]);
      float a3 = (s0[3][0] + s0[3][1]) + (s0[3][2] + s0[3][3]);
      l0 += (a0 + a1) + (a2 + a3);
      float b0 = (s1[0][0] + s1[0][1]) + (s1[0][2] + s1[0][3]);
      float b1 = (s1[1][0] + s1[1][1]) + (s1[1][2] + s1[1][3]);
      float b2 = (s1[2][0] + s1[2][1]) + (s1[2][2] + s1[2][3]);
      float b3 = (s1[3][0] + s1[3][1]) + (s1[3][2] + s1[3][3]);
      l1 += (b0 + b1) + (b2 + b3);
    }

    bf16x8 pa0[2], pa1[2];
#pragma unroll
    for (int c = 0; c < 2; ++c) {
      u32x4 w0, w1;
      w0[0] = pack_bf16(s0[2 * c][0], s0[2 * c][1]);
      w0[1] = pack_bf16(s0[2 * c][2], s0[2 * c][3]);
      w0[2] = pack_bf16(s0[2 * c + 1][0], s0[2 * c + 1][1]);
      w0[3] = pack_bf16(s0[2 * c + 1][2], s0[2 * c + 1][3]);
      pa0[c] = __builtin_bit_cast(bf16x8, w0);
      w1[0] = pack_bf16(s1[2 * c][0], s1[2 * c][1]);
      w1[1] = pack_bf16(s1[2 * c][2], s1[2 * c][3]);
      w1[2] = pack_bf16(s1[2 * c + 1][0], s1[2 * c + 1][1]);
      w1[3] = pack_bf16(s1[2 * c + 1][2], s1[2 * c + 1][3]);
      pa1[c] = __builtin_bit_cast(bf16x8, w1);
    }

    __builtin_amdgcn_s_setprio(1);
#pragma unroll
    for (int nd = 0; nd < 4; ++nd)
#pragma unroll
      for (int c = 0; c < 2; ++c) {
        o0[nd] = __builtin_amdgcn_mfma_f32_16x16x32_bf16(av[nd][c], pa0[c], o0[nd], 0, 0, 0);
        o1[nd] = __builtin_amdgcn_mfma_f32_16x16x32_bf16(av[nd][c], pa1[c], o1[nd], 0, 0, 0);
      }
    __builtin_amdgcn_s_setprio(0);
  };

  stage(0, smem[0]);
  __syncthreads();

  for (int it = 0; it < 7; ++it) {
    stage((2 * it + 1) * 128, smem[1]);
    compute(kA0, kB0);
    compute(kA0 + 16384, kB0 + 16384);
    __syncthreads();
    stage((2 * it + 2) * 128, smem[0]);
    compute(kA1, kB1);
    compute(kA1 + 16384, kB1 + 16384);
    __syncthreads();
  }
  stage(1920, smem[1]);                 // tile 15 (kv 1920..2047)
  compute(kA0, kB0);
  compute(kA0 + 16384, kB0 + 16384);
  __syncthreads();
  compute(kA1, kB1);
  compute(kA1 + 16384, kB1 + 16384);

  l0 += __shfl_xor(l0, 16); l0 += __shfl_xor(l0, 32);
  l1 += __shfl_xor(l1, 16); l1 += __shfl_xor(l1, 32);
  const float inv0 = 1.0f / l0, inv1 = 1.0f / l1;

#pragma unroll
  for (int nd = 0; nd < 4; ++nd) {
    uint2 st;
    st.x = pack_bf16(o0[nd][0] * inv0, o0[nd][1] * inv0);
    st.y = pack_bf16(o0[nd][2] * inv0, o0[nd][3] * inv0);
    *reinterpret_cast<uint2*>(
        &O[(size_t)(b * T + t0 + lr) * C + h * DH + nd * 16 + lg * 4]) = st;
    st.x = pack_bf16(o1[nd][0] * inv1, o1[nd][1] * inv1);
    st.y = pack_bf16(o1[nd][2] * inv1, o1[nd][3] * inv1);
    *reinterpret_cast<uint2*>(
        &O[(size_t)(b * T + t0 + 16 + lr) * C + h * DH + nd * 16 + lg * 4]) = st;
  }
}

extern "C" void kernel_launch(void* const* d_in, const int* in_sizes, int n_in,
                              void* d_out, int out_size, void* d_ws, size_t ws_size,
                              hipStream_t stream) {
  const float* x      = (const float*)d_in[0];
  const float* w_qkv  = (const float*)d_in[1];
  const float* b_qkv  = (const float*)d_in[2];
  const float* w_proj = (const float*)d_in[3];
  const float* b_proj = (const float*)d_in[4];
  float* out = (float*)d_out;

  // workspace layout (bf16 elems), total 50.3 MB
  __hip_bfloat16* ws  = (__hip_bfloat16*)d_ws;
  __hip_bfloat16* xb  = ws;                    // 4194304  x as bf16 [4096][1024]
  __hip_bfloat16* wqt = xb + 4194304;          // 3145728  w_qkv^T [3072][1024]
  __hip_bfloat16* wpt = wqt + 3145728;         // 1048576  w_proj^T [1024][1024]
  __hip_bfloat16* Qb  = wpt + 1048576;         // 4194304  Q [b,h,t,d] (x 0.125*log2e)
  __hip_bfloat16* Kb  = Qb + 4194304;          // 4194304  K [b,h,t,d]
  __hip_bfloat16* Vtb = Kb + 4194304;          // 4194304  V^T [b,h,d,t'] kv-permuted
  __hip_bfloat16* Ob  = Vtb + 4194304;         // 4194304  attn out [4096][1024]

  k_prep<<<8192, 256, 0, stream>>>(x, xb, w_qkv, wqt, w_proj, wpt);
  k_gemmqkv<<<dim3(32, 24), 256, 0, stream>>>(xb, wqt, b_qkv, Qb, Kb, Vtb);
  k_attn<<<512, 256, 0, stream>>>(Qb, Kb, Vtb, Ob);
  k_gemmproj<<<dim3(32, 8), 256, 0, stream>>>(Ob, wpt, b_proj, out);
}

// Round 20
// 101.748 us; speedup vs baseline: 1.0219x; 1.0219x over previous
//
#include <hip/hip_runtime.h>
#include <hip/hip_bf16.h>

typedef __attribute__((ext_vector_type(8))) short bf16x8;
typedef __attribute__((ext_vector_type(4))) float f32x4;
typedef __attribute__((ext_vector_type(4))) unsigned int u32x4;

static constexpr int BB = 2, T = 2048, C = 1024, NH = 16, DH = 64;

__device__ __forceinline__ void gload16(const void* g, void* l) {
  __builtin_amdgcn_global_load_lds(
      (const __attribute__((address_space(1))) unsigned int*)g,
      (__attribute__((address_space(3))) unsigned int*)l, 16, 0, 0);
}

__device__ __forceinline__ unsigned pack_bf16(float lo, float hi) {
  unsigned a = (unsigned)__bfloat16_as_ushort(__float2bfloat16(lo));
  unsigned b = (unsigned)__bfloat16_as_ushort(__float2bfloat16(hi));
  return a | (b << 16);
}

__device__ __forceinline__ float fast_exp2(float x) {
#if __has_builtin(__builtin_amdgcn_exp2f)
  return __builtin_amdgcn_exp2f(x);
#else
  return exp2f(x);
#endif
}

// ---------------- fused prep: x cvt + both weight transposes ----------------
__global__ __launch_bounds__(256) void k_prep(const float* __restrict__ x,
                                              __hip_bfloat16* __restrict__ xb,
                                              const float* __restrict__ wq,
                                              __hip_bfloat16* __restrict__ wqt,
                                              const float* __restrict__ wp,
                                              __hip_bfloat16* __restrict__ wpt) {
  __shared__ float tile[32][33];
  const int bid = blockIdx.x, tid = threadIdx.x;
  if (bid < 4096) {
    const int i = bid * 256 + tid;
    float4 v = reinterpret_cast<const float4*>(x)[i];
    __hip_bfloat16 h[4];
    h[0] = __float2bfloat16(v.x); h[1] = __float2bfloat16(v.y);
    h[2] = __float2bfloat16(v.z); h[3] = __float2bfloat16(v.w);
    reinterpret_cast<uint2*>(xb)[i] = *reinterpret_cast<uint2*>(h);
    return;
  }
  const float* in;
  __hip_bfloat16* out;
  int K, N, bx, by;
  if (bid < 7168) {
    const int b2 = bid - 4096;
    in = wq; out = wqt; K = 1024; N = 3072; bx = b2 % 96; by = b2 / 96;
  } else {
    const int b2 = bid - 7168;
    in = wp; out = wpt; K = 1024; N = 1024; bx = b2 % 32; by = b2 / 32;
  }
  const int n0 = bx * 32, k0 = by * 32;
  const int tx = tid & 31, ty = tid >> 5;  // 32 x 8
#pragma unroll
  for (int i = 0; i < 32; i += 8)
    tile[ty + i][tx] = in[(size_t)(k0 + ty + i) * N + n0 + tx];
  __syncthreads();
#pragma unroll
  for (int i = 0; i < 32; i += 8)
    out[(size_t)(n0 + ty + i) * K + k0 + tx] = __float2bfloat16(tile[tx][ty + i]);
}

// ---------------- QKV GEMM: 128x128 tile, BK=64, 4 waves, 2 blocks/CU -------------
// r13-proven K-loop. Epilogue: Q/K direct scatter; V via per-wave LDS transpose.
__global__ __launch_bounds__(256, 2) void k_gemmqkv(
    const __hip_bfloat16* __restrict__ A, const __hip_bfloat16* __restrict__ Bt,
    const float* __restrict__ bias,
    __hip_bfloat16* __restrict__ oq, __hip_bfloat16* __restrict__ okk,
    __hip_bfloat16* __restrict__ ovt) {
  __shared__ __align__(16) char smem[65536];  // [buf][A 16K | B 16K]
  const int tid = threadIdx.x;
  const int w = tid >> 6, lane = tid & 63;
  const int lr = lane & 15, lg = lane >> 4;
  const int wm = (w >> 1) * 64, wn = (w & 1) * 64;
  const int m0 = blockIdx.x * 128, n0 = blockIdx.y * 128;

  const int scol = (((tid & 7) ^ ((tid >> 3) & 7)) << 4);
  const char* Ag = (const char*)A + (size_t)(m0 + (tid >> 3)) * 2048 + scol;
  const char* Bg = (const char*)Bt + (size_t)(n0 + (tid >> 3)) * 2048 + scol;
  const size_t ldst = (size_t)(tid & ~63) * 16;  // wave-uniform LDS base

  auto stage = [&](int ks, char* lA) {  // A at +0, B at +16384
    const char* ag = Ag + (size_t)ks * 128;
    const char* bg = Bg + (size_t)ks * 128;
    char* lB = lA + 16384;
#pragma unroll
    for (int j = 0; j < 4; ++j) {
      gload16(ag + (size_t)j * 65536, lA + j * 4096 + ldst);
      gload16(bg + (size_t)j * 65536, lB + j * 4096 + ldst);
    }
  };

  const int swz = (lr & 7) << 4;
  const int aofs = (wm + lr) * 128;
  const int bofs = 16384 + (wn + lr) * 128;
  const int x0 = (lg * 16) ^ swz;
  const int x1 = (64 + lg * 16) ^ swz;
  const char* A00 = smem + aofs + x0;
  const char* A01 = smem + aofs + x1;
  const char* B00 = smem + bofs + x0;
  const char* B01 = smem + bofs + x1;
  const char* A10 = A00 + 32768;
  const char* A11 = A01 + 32768;
  const char* B10 = B00 + 32768;
  const char* B11 = B01 + 32768;

  f32x4 acc[4][4] = {};

  auto compute = [&](const char* pA0, const char* pA1, const char* pB0,
                     const char* pB1) {
#pragma unroll
    for (int kk = 0; kk < 2; ++kk) {
      const char* pA = kk ? pA1 : pA0;
      const char* pB = kk ? pB1 : pB0;
      bf16x8 a[4], b[4];
#pragma unroll
      for (int mi = 0; mi < 4; ++mi)
        a[mi] = *reinterpret_cast<const bf16x8*>(pA + mi * 2048);
#pragma unroll
      for (int ni = 0; ni < 4; ++ni)
        b[ni] = *reinterpret_cast<const bf16x8*>(pB + ni * 2048);
      __builtin_amdgcn_s_setprio(1);
#pragma unroll
      for (int mi = 0; mi < 4; ++mi)
#pragma unroll
        for (int ni = 0; ni < 4; ++ni)
          acc[mi][ni] =
              __builtin_amdgcn_mfma_f32_16x16x32_bf16(a[mi], b[ni], acc[mi][ni], 0, 0, 0);
      __builtin_amdgcn_s_setprio(0);
    }
  };

  stage(0, smem);
  __syncthreads();
  for (int it = 0; it < 8; ++it) {
    stage(2 * it + 1, smem + 32768);
    compute(A00, A01, B00, B01);
    __syncthreads();
    if (it < 7) stage(2 * it + 2, smem);
    compute(A10, A11, B10, B11);
    __syncthreads();
  }

  const int region = n0 >> 10;  // 0=Q 1=K 2=V
  float bias_r[4];
#pragma unroll
  for (int ni = 0; ni < 4; ++ni) bias_r[ni] = bias[n0 + wn + ni * 16 + lr];

  if (region < 2) {
    __hip_bfloat16* dst = (region == 0) ? oq : okk;
    const float sc = (region == 0) ? 0.1803368801111244f : 1.0f;
#pragma unroll
    for (int mi = 0; mi < 4; ++mi) {
#pragma unroll
      for (int ni = 0; ni < 4; ++ni) {
        const int nn = n0 + wn + ni * 16 + lr;
        const int cc = nn & 1023, h = cc >> 6, d = cc & 63;
#pragma unroll
        for (int r = 0; r < 4; ++r) {
          const int m = m0 + wm + mi * 16 + lg * 4 + r;
          const int bb = m >> 11, t = m & 2047;
          dst[((size_t)(bb * NH + h) * T + t) * DH + d] =
              __float2bfloat16((acc[mi][ni][r] + bias_r[ni]) * sc);
        }
      }
    }
  } else {
    char* E = smem + w * 8192;
#pragma unroll
    for (int mi = 0; mi < 4; ++mi) {
      const int mlb = mi * 16 + lg * 4;
      const int mp = (mlb & 35) | ((mlb & 12) << 1) | ((mlb & 16) >> 2);
#pragma unroll
      for (int ni = 0; ni < 4; ++ni) {
        const int dl = ni * 16 + lr;
        const int rs = (dl & 7) << 4;
        const unsigned v01 = pack_bf16(acc[mi][ni][0] + bias_r[ni],
                                       acc[mi][ni][1] + bias_r[ni]);
        const unsigned v23 = pack_bf16(acc[mi][ni][2] + bias_r[ni],
                                       acc[mi][ni][3] + bias_r[ni]);
        *reinterpret_cast<unsigned*>(&E[dl * 128 + ((mp * 2) ^ rs)]) = v01;
        *reinterpret_cast<unsigned*>(&E[dl * 128 + (((mp + 2) * 2) ^ rs)]) = v23;
      }
    }
    const int hh = ((n0 + wn) & 1023) >> 6;
    const int bb = m0 >> 11, tb = (m0 & 2047) + wm;
    __hip_bfloat16* dst = ovt + ((size_t)(bb * NH + hh) * DH) * T + tb;
    const int lrs = (lane & 7) << 4;
#pragma unroll
    for (int j = 0; j < 8; ++j) {
      u32x4 v = *reinterpret_cast<const u32x4*>(&E[lane * 128 + ((j * 16) ^ lrs)]);
      *reinterpret_cast<u32x4*>(&dst[(size_t)lane * T + j * 8]) = v;
    }
  }
}

// ---------------- proj GEMM: r13 BK=64 skeleton, fp32 out + bias ------------------
__global__ __launch_bounds__(256, 2) void k_gemmproj(
    const __hip_bfloat16* __restrict__ A, const __hip_bfloat16* __restrict__ Bt,
    const float* __restrict__ bias, float* __restrict__ of) {
  constexpr int N = 1024;
  __shared__ __align__(16) char smem[65536];
  const int tid = threadIdx.x;
  const int w = tid >> 6, lane = tid & 63;
  const int lr = lane & 15, lg = lane >> 4;
  const int wm = (w >> 1) * 64, wn = (w & 1) * 64;
  const int m0 = blockIdx.x * 128, n0 = blockIdx.y * 128;

  const int scol = (((tid & 7) ^ ((tid >> 3) & 7)) << 4);
  const char* Ag = (const char*)A + (size_t)(m0 + (tid >> 3)) * 2048 + scol;
  const char* Bg = (const char*)Bt + (size_t)(n0 + (tid >> 3)) * 2048 + scol;
  const size_t ldst = (size_t)(tid & ~63) * 16;

  auto stage = [&](int ks, char* lA) {
    const char* ag = Ag + (size_t)ks * 128;
    const char* bg = Bg + (size_t)ks * 128;
    char* lB = lA + 16384;
#pragma unroll
    for (int j = 0; j < 4; ++j) {
      gload16(ag + (size_t)j * 65536, lA + j * 4096 + ldst);
      gload16(bg + (size_t)j * 65536, lB + j * 4096 + ldst);
    }
  };

  const int swz = (lr & 7) << 4;
  const int aofs = (wm + lr) * 128;
  const int bofs = 16384 + (wn + lr) * 128;
  const int x0 = (lg * 16) ^ swz;
  const int x1 = (64 + lg * 16) ^ swz;
  const char* A00 = smem + aofs + x0;
  const char* A01 = smem + aofs + x1;
  const char* B00 = smem + bofs + x0;
  const char* B01 = smem + bofs + x1;
  const char* A10 = A00 + 32768;
  const char* A11 = A01 + 32768;
  const char* B10 = B00 + 32768;
  const char* B11 = B01 + 32768;

  f32x4 acc[4][4] = {};

  auto compute = [&](const char* pA0, const char* pA1, const char* pB0,
                     const char* pB1) {
#pragma unroll
    for (int kk = 0; kk < 2; ++kk) {
      const char* pA = kk ? pA1 : pA0;
      const char* pB = kk ? pB1 : pB0;
      bf16x8 a[4], b[4];
#pragma unroll
      for (int mi = 0; mi < 4; ++mi)
        a[mi] = *reinterpret_cast<const bf16x8*>(pA + mi * 2048);
#pragma unroll
      for (int ni = 0; ni < 4; ++ni)
        b[ni] = *reinterpret_cast<const bf16x8*>(pB + ni * 2048);
      __builtin_amdgcn_s_setprio(1);
#pragma unroll
      for (int mi = 0; mi < 4; ++mi)
#pragma unroll
        for (int ni = 0; ni < 4; ++ni)
          acc[mi][ni] =
              __builtin_amdgcn_mfma_f32_16x16x32_bf16(a[mi], b[ni], acc[mi][ni], 0, 0, 0);
      __builtin_amdgcn_s_setprio(0);
    }
  };

  stage(0, smem);
  __syncthreads();
  for (int it = 0; it < 8; ++it) {
    stage(2 * it + 1, smem + 32768);
    compute(A00, A01, B00, B01);
    __syncthreads();
    if (it < 7) stage(2 * it + 2, smem);
    compute(A10, A11, B10, B11);
    __syncthreads();
  }

  float bias_r[4];
#pragma unroll
  for (int ni = 0; ni < 4; ++ni) bias_r[ni] = bias[n0 + wn + ni * 16 + lr];

#pragma unroll
  for (int mi = 0; mi < 4; ++mi)
#pragma unroll
    for (int ni = 0; ni < 4; ++ni) {
      const int n = n0 + wn + ni * 16 + lr;
#pragma unroll
      for (int r = 0; r < 4; ++r) {
        const int m = m0 + wm + mi * 16 + lg * 4 + r;
        of[(size_t)m * N + n] = acc[mi][ni][r] + bias_r[ni];
      }
    }
}

// ---------------- flash attention v9 (r18 exact revert): 32q/wave sharing K/V -----
__global__ __launch_bounds__(256, 2) void k_attn(const __hip_bfloat16* __restrict__ Q,
                                                 const __hip_bfloat16* __restrict__ Kc,
                                                 const __hip_bfloat16* __restrict__ Vt,
                                                 __hip_bfloat16* __restrict__ O) {
  __shared__ __align__(16) char smem[2][16384];  // [buf][K 8KB | V 8KB]
  const int tid = threadIdx.x;
  const int w = tid >> 6, lane = tid & 63;
  const int lr = lane & 15, lg = lane >> 4;
  const int n = blockIdx.x;                       // 512 blocks, 1-D
  const int xtile = (n >> 3) & 15;
  const int bh = ((n >> 7) << 3) | (n & 7);
  const int b = bh >> 4, h = bh & 15;
  const int t0 = xtile * 128 + w * 32;
  const __hip_bfloat16* Qh = Q + (size_t)bh * T * DH;
  const char* Kbase = (const char*)(Kc + (size_t)bh * T * DH);   // rows of 128B
  const char* Vbase = (const char*)(Vt + (size_t)bh * DH * T);   // rows of 4096B

  const int srow = tid >> 3;
  const int scol = (((tid & 7) ^ (srow & 7)) << 4);
  const size_t ldst = (size_t)(tid & ~63) * 16;
  const char* Kg = Kbase + (size_t)srow * 128 + scol;
  const char* Vg = Vbase + (size_t)srow * 4096 + scol;

  const int swz = (lr & 7) << 4;
  const int lbA = lr * 128 + ((lg * 16) ^ swz);
  const int lbB = lr * 128 + ((64 + lg * 16) ^ swz);
  const char* kA0 = smem[0] + lbA;
  const char* kB0 = smem[0] + lbB;
  const char* kA1 = smem[1] + lbA;
  const char* kB1 = smem[1] + lbB;

  auto stage = [&](int kv, char* kb, char* vb) {
    const char* kg = Kg + (size_t)kv * 128;
    const char* vg = Vg + (size_t)kv * 2;
    gload16(kg, kb + ldst);
    gload16(kg + 4096, kb + 4096 + ldst);
    gload16(vg, vb + ldst);
    gload16(vg + 131072, vb + 4096 + ldst);
  };

  bf16x8 q0[2], q1[2];
#pragma unroll
  for (int kf = 0; kf < 2; ++kf) {
    q0[kf] = *reinterpret_cast<const bf16x8*>(&Qh[(size_t)(t0 + lr) * DH + kf * 32 + lg * 8]);
    q1[kf] = *reinterpret_cast<const bf16x8*>(&Qh[(size_t)(t0 + 16 + lr) * DH + kf * 32 + lg * 8]);
  }

  f32x4 o0[4] = {}, o1[4] = {};
  float l0 = 0.f, l1 = 0.f;

  auto compute = [&](const char* kA, const char* kB) {
    bf16x8 bk[4][2];
#pragma unroll
    for (int nj = 0; nj < 4; ++nj) {
      bk[nj][0] = *reinterpret_cast<const bf16x8*>(kA + nj * 2048);
      bk[nj][1] = *reinterpret_cast<const bf16x8*>(kB + nj * 2048);
    }

    f32x4 s0[4] = {}, s1[4] = {};
    __builtin_amdgcn_s_setprio(1);
#pragma unroll
    for (int nj = 0; nj < 4; ++nj) {
      s0[nj] = __builtin_amdgcn_mfma_f32_16x16x32_bf16(bk[nj][0], q0[0], s0[nj], 0, 0, 0);
      s0[nj] = __builtin_amdgcn_mfma_f32_16x16x32_bf16(bk[nj][1], q0[1], s0[nj], 0, 0, 0);
      s1[nj] = __builtin_amdgcn_mfma_f32_16x16x32_bf16(bk[nj][0], q1[0], s1[nj], 0, 0, 0);
      s1[nj] = __builtin_amdgcn_mfma_f32_16x16x32_bf16(bk[nj][1], q1[1], s1[nj], 0, 0, 0);
    }
    __builtin_amdgcn_s_setprio(0);

    bf16x8 av[4][2];
#pragma unroll
    for (int nd = 0; nd < 4; ++nd) {
      av[nd][0] = *reinterpret_cast<const bf16x8*>(kA + 8192 + nd * 2048);
      av[nd][1] = *reinterpret_cast<const bf16x8*>(kB + 8192 + nd * 2048);
    }

#pragma unroll
    for (int nj = 0; nj < 4; ++nj)
#pragma unroll
      for (int r = 0; r < 4; ++r) {
        s0[nj][r] = fast_exp2(s0[nj][r]);
        s1[nj][r] = fast_exp2(s1[nj][r]);
      }
    {
      float a0 = (s0[0][0] + s0[0][1]) + (s0[0][2] + s0[0][3]);
      float a1 = (s0[1][0] + s0[1][1]) + (s0[1][2] + s0[1][3]);
      float a2 = (s0[2][0] + s0[2][1]) + (s0[2][2] + s0[2][3]);
      float a3 = (s0[3][0] + s0[3][1]) + (s0[3][2] + s0[3][3]);
      l0 += (a0 + a1) + (a2 + a3);
      float b0 = (s1[0][0] + s1[0][1]) + (s1[0][2] + s1[0][3]);
      float b1 = (s1[1][0] + s1[1][1]) + (s1[1][2] + s1[1][3]);
      float b2 = (s1[2][0] + s1[2][1]) + (s1[2][2] + s1[2][3]);
      float b3 = (s1[3][0] + s1[3][1]) + (s1[3][2] + s1[3][3]);
      l1 += (b0 + b1) + (b2 + b3);
    }

    bf16x8 pa0[2], pa1[2];
#pragma unroll
    for (int c = 0; c < 2; ++c) {
      u32x4 w0, w1;
      w0[0] = pack_bf16(s0[2 * c][0], s0[2 * c][1]);
      w0[1] = pack_bf16(s0[2 * c][2], s0[2 * c][3]);
      w0[2] = pack_bf16(s0[2 * c + 1][0], s0[2 * c + 1][1]);
      w0[3] = pack_bf16(s0[2 * c + 1][2], s0[2 * c + 1][3]);
      pa0[c] = __builtin_bit_cast(bf16x8, w0);
      w1[0] = pack_bf16(s1[2 * c][0], s1[2 * c][1]);
      w1[1] = pack_bf16(s1[2 * c][2], s1[2 * c][3]);
      w1[2] = pack_bf16(s1[2 * c + 1][0], s1[2 * c + 1][1]);
      w1[3] = pack_bf16(s1[2 * c + 1][2], s1[2 * c + 1][3]);
      pa1[c] = __builtin_bit_cast(bf16x8, w1);
    }

    __builtin_amdgcn_s_setprio(1);
#pragma unroll
    for (int nd = 0; nd < 4; ++nd)
#pragma unroll
      for (int c = 0; c < 2; ++c) {
        o0[nd] = __builtin_amdgcn_mfma_f32_16x16x32_bf16(av[nd][c], pa0[c], o0[nd], 0, 0, 0);
        o1[nd] = __builtin_amdgcn_mfma_f32_16x16x32_bf16(av[nd][c], pa1[c], o1[nd], 0, 0, 0);
      }
    __builtin_amdgcn_s_setprio(0);
  };

  stage(0, smem[0], smem[0] + 8192);
  __syncthreads();

  for (int it = 0; it < 15; ++it) {
    const int kv = it * 128;
    stage(kv + 64, smem[1], smem[1] + 8192);
    compute(kA0, kB0);
    __syncthreads();
    stage(kv + 128, smem[0], smem[0] + 8192);
    compute(kA1, kB1);
    __syncthreads();
  }
  stage(1984, smem[1], smem[1] + 8192);
  compute(kA0, kB0);
  __syncthreads();
  compute(kA1, kB1);

  l0 += __shfl_xor(l0, 16); l0 += __shfl_xor(l0, 32);
  l1 += __shfl_xor(l1, 16); l1 += __shfl_xor(l1, 32);
  const float inv0 = 1.0f / l0, inv1 = 1.0f / l1;

#pragma unroll
  for (int nd = 0; nd < 4; ++nd) {
    uint2 st;
    st.x = pack_bf16(o0[nd][0] * inv0, o0[nd][1] * inv0);
    st.y = pack_bf16(o0[nd][2] * inv0, o0[nd][3] * inv0);
    *reinterpret_cast<uint2*>(
        &O[(size_t)(b * T + t0 + lr) * C + h * DH + nd * 16 + lg * 4]) = st;
    st.x = pack_bf16(o1[nd][0] * inv1, o1[nd][1] * inv1);
    st.y = pack_bf16(o1[nd][2] * inv1, o1[nd][3] * inv1);
    *reinterpret_cast<uint2*>(
        &O[(size_t)(b * T + t0 + 16 + lr) * C + h * DH + nd * 16 + lg * 4]) = st;
  }
}

extern "C" void kernel_launch(void* const* d_in, const int* in_sizes, int n_in,
                              void* d_out, int out_size, void* d_ws, size_t ws_size,
                              hipStream_t stream) {
  const float* x      = (const float*)d_in[0];
  const float* w_qkv  = (const float*)d_in[1];
  const float* b_qkv  = (const float*)d_in[2];
  const float* w_proj = (const float*)d_in[3];
  const float* b_proj = (const float*)d_in[4];
  float* out = (float*)d_out;

  // workspace layout (bf16 elems), total 50.3 MB
  __hip_bfloat16* ws  = (__hip_bfloat16*)d_ws;
  __hip_bfloat16* xb  = ws;                    // 4194304  x as bf16 [4096][1024]
  __hip_bfloat16* wqt = xb + 4194304;          // 3145728  w_qkv^T [3072][1024]
  __hip_bfloat16* wpt = wqt + 3145728;         // 1048576  w_proj^T [1024][1024]
  __hip_bfloat16* Qb  = wpt + 1048576;         // 4194304  Q [b,h,t,d] (x 0.125*log2e)
  __hip_bfloat16* Kb  = Qb + 4194304;          // 4194304  K [b,h,t,d]
  __hip_bfloat16* Vtb = Kb + 4194304;          // 4194304  V^T [b,h,d,t'] kv-permuted
  __hip_bfloat16* Ob  = Vtb + 4194304;         // 4194304  attn out [4096][1024]

  k_prep<<<8192, 256, 0, stream>>>(x, xb, w_qkv, wqt, w_proj, wpt);
  k_gemmqkv<<<dim3(32, 24), 256, 0, stream>>>(xb, wqt, b_qkv, Qb, Kb, Vtb);
  k_attn<<<512, 256, 0, stream>>>(Qb, Kb, Vtb, Ob);
  k_gemmproj<<<dim3(32, 8), 256, 0, stream>>>(Ob, wpt, b_proj, out);
}